// Round 4
// baseline (186.872 us; speedup 1.0000x reference)
//
#include <hip/hip_runtime.h>
#include <hip/hip_bf16.h>

#define N_NODES 2048
#define EMB 768
#define NH 8
#define DH 96
#define ALPHA 0.2f
#define SCALE 0.10206207261596575f  // 96^-0.5

typedef __bf16 bf16x8 __attribute__((ext_vector_type(8)));
typedef float f32x4 __attribute__((ext_vector_type(4)));

union pack4 { ushort4 u; __hip_bfloat16 h[4]; };

// ---------------------------------------------------------------- concat (f32 -> bf16) + zero counters
__global__ __launch_bounds__(256) void concat_cast_kernel(
    const float* __restrict__ eh, const float* __restrict__ er,
    const float* __restrict__ et, __hip_bfloat16* __restrict__ e, int* __restrict__ cnt)
{
    int tid = blockIdx.x * 256 + threadIdx.x;   // 393,216 threads, 4 elems each
    if (tid < 32) cnt[tid] = 0;
    int idx = tid * 4;
    int i = idx / EMB;
    int c = idx % EMB;
    const float* src;
    if (c < 256)      src = eh + i * 256 + c;
    else if (c < 512) src = er + i * 256 + (c - 256);
    else              src = et + i * 256 + (c - 512);
    float4 v = *reinterpret_cast<const float4*>(src);
    pack4 p;
    p.h[0] = __float2bfloat16(v.x);
    p.h[1] = __float2bfloat16(v.y);
    p.h[2] = __float2bfloat16(v.z);
    p.h[3] = __float2bfloat16(v.w);
    *reinterpret_cast<ushort4*>(e + (size_t)i * EMB + c) = p.u;
}

// ---------------------------------------------------------------- cast 3 weight matrices f32 -> bf16
__global__ __launch_bounds__(256) void cast_w_kernel(
    const float* __restrict__ w0, const float* __restrict__ w1, const float* __restrict__ w2,
    __hip_bfloat16* __restrict__ o0, __hip_bfloat16* __restrict__ o1, __hip_bfloat16* __restrict__ o2)
{
    const int WSZ = EMB * EMB;  // 589,824
    int idx = (blockIdx.x * 256 + threadIdx.x) * 4;  // 1728 blocks -> 1,769,472 elems
    const float* src;
    __hip_bfloat16* dst;
    if (idx < WSZ)              { src = w0 + idx;           dst = o0 + idx; }
    else if (idx < 2 * WSZ)     { src = w1 + idx - WSZ;     dst = o1 + idx - WSZ; }
    else                        { src = w2 + idx - 2 * WSZ; dst = o2 + idx - 2 * WSZ; }
    float4 v = *reinterpret_cast<const float4*>(src);
    pack4 p;
    p.h[0] = __float2bfloat16(v.x);
    p.h[1] = __float2bfloat16(v.y);
    p.h[2] = __float2bfloat16(v.z);
    p.h[3] = __float2bfloat16(v.w);
    *reinterpret_cast<ushort4*>(dst) = p.u;
}

// ---------------------------------------------------------------- MFMA GEMM, C = A1@B1^T [+ A2@B2^T] [+ bias1+bias2]
// A: M x K row-major bf16, B: N x K row-major bf16 (C[i,c] = sum_k A[i,k]*B[c,k])
// Block computes 64x64 tile; 4 waves in 2x2; each wave 2x2 of 16x16x32 MFMAs.
// Output is ALWAYS f32.
__global__ __launch_bounds__(256) void gemm_nt_kernel(
    const __hip_bfloat16* __restrict__ A1, const __hip_bfloat16* __restrict__ B1, int K1,
    const __hip_bfloat16* __restrict__ A2, const __hip_bfloat16* __restrict__ B2, int K2,
    const float* __restrict__ bias1, const float* __restrict__ bias2,
    float* __restrict__ Cf, int N)
{
    const int lane = threadIdx.x & 63;
    const int wave = threadIdx.x >> 6;
    const int wm = wave >> 1, wn = wave & 1;
    const int bm = blockIdx.y * 64, bn = blockIdx.x * 64;
    const int l15 = lane & 15, quad = lane >> 4;

    f32x4 acc00 = {0.f, 0.f, 0.f, 0.f};
    f32x4 acc01 = {0.f, 0.f, 0.f, 0.f};
    f32x4 acc10 = {0.f, 0.f, 0.f, 0.f};
    f32x4 acc11 = {0.f, 0.f, 0.f, 0.f};

    {
        const __hip_bfloat16* pA0 = A1 + (size_t)(bm + wm * 32 + l15) * K1 + quad * 8;
        const __hip_bfloat16* pA1 = pA0 + (size_t)16 * K1;
        const __hip_bfloat16* pB0 = B1 + (size_t)(bn + wn * 32 + l15) * K1 + quad * 8;
        const __hip_bfloat16* pB1 = pB0 + (size_t)16 * K1;
        for (int k0 = 0; k0 < K1; k0 += 32) {
            bf16x8 a0 = *reinterpret_cast<const bf16x8*>(pA0 + k0);
            bf16x8 a1 = *reinterpret_cast<const bf16x8*>(pA1 + k0);
            bf16x8 b0 = *reinterpret_cast<const bf16x8*>(pB0 + k0);
            bf16x8 b1 = *reinterpret_cast<const bf16x8*>(pB1 + k0);
            acc00 = __builtin_amdgcn_mfma_f32_16x16x32_bf16(a0, b0, acc00, 0, 0, 0);
            acc01 = __builtin_amdgcn_mfma_f32_16x16x32_bf16(a0, b1, acc01, 0, 0, 0);
            acc10 = __builtin_amdgcn_mfma_f32_16x16x32_bf16(a1, b0, acc10, 0, 0, 0);
            acc11 = __builtin_amdgcn_mfma_f32_16x16x32_bf16(a1, b1, acc11, 0, 0, 0);
        }
    }
    if (K2 > 0) {
        const __hip_bfloat16* pA0 = A2 + (size_t)(bm + wm * 32 + l15) * K2 + quad * 8;
        const __hip_bfloat16* pA1 = pA0 + (size_t)16 * K2;
        const __hip_bfloat16* pB0 = B2 + (size_t)(bn + wn * 32 + l15) * K2 + quad * 8;
        const __hip_bfloat16* pB1 = pB0 + (size_t)16 * K2;
        for (int k0 = 0; k0 < K2; k0 += 32) {
            bf16x8 a0 = *reinterpret_cast<const bf16x8*>(pA0 + k0);
            bf16x8 a1 = *reinterpret_cast<const bf16x8*>(pA1 + k0);
            bf16x8 b0 = *reinterpret_cast<const bf16x8*>(pB0 + k0);
            bf16x8 b1 = *reinterpret_cast<const bf16x8*>(pB1 + k0);
            acc00 = __builtin_amdgcn_mfma_f32_16x16x32_bf16(a0, b0, acc00, 0, 0, 0);
            acc01 = __builtin_amdgcn_mfma_f32_16x16x32_bf16(a0, b1, acc01, 0, 0, 0);
            acc10 = __builtin_amdgcn_mfma_f32_16x16x32_bf16(a1, b0, acc10, 0, 0, 0);
            acc11 = __builtin_amdgcn_mfma_f32_16x16x32_bf16(a1, b1, acc11, 0, 0, 0);
        }
    }

    const int col0 = bn + wn * 32 + l15;
    const int col1 = col0 + 16;
    float bv0 = 0.f, bv1 = 0.f;
    if (bias1 != nullptr) {
        bv0 = bias1[col0] + bias2[col0];
        bv1 = bias1[col1] + bias2[col1];
    }
    const int r0 = bm + wm * 32 + quad * 4;
#pragma unroll
    for (int r = 0; r < 4; r++) {
        const int row0 = r0 + r, row1 = r0 + 16 + r;
        Cf[(size_t)row0 * N + col0] = acc00[r] + bv0;
        Cf[(size_t)row0 * N + col1] = acc01[r] + bv1;
        Cf[(size_t)row1 * N + col0] = acc10[r] + bv0;
        Cf[(size_t)row1 * N + col1] = acc11[r] + bv1;
    }
}

// ---------------------------------------------------------------- s1/s2 = Wh . a1 / a2  (all f32)
__global__ __launch_bounds__(256) void s12_kernel(
    const float* __restrict__ Wh, const float* __restrict__ a,
    float* __restrict__ s1, float* __restrict__ s2)
{
    int gid = blockIdx.x * 256 + threadIdx.x;  // [0, N*NH)
    int i = gid >> 3, h = gid & 7;
    const float* wr = Wh + (size_t)i * EMB + h * DH;
    float acc1 = 0.f, acc2 = 0.f;
    for (int d = 0; d < DH; d++) {
        float w = wr[d];
        acc1 += w * a[d];
        acc2 += w * a[DH + d];
    }
    s1[gid] = acc1;
    s2[gid] = acc2;
}

// ---------------------------------------------------------------- build per-group node lists
__global__ __launch_bounds__(256) void group_kernel(
    const int* __restrict__ h_id, int* __restrict__ cnt, int* __restrict__ lists)
{
    int i = blockIdx.x * 256 + threadIdx.x;
    if (i < N_NODES) {
        int g = h_id[i];
        int p = atomicAdd(&cnt[g], 1);
        lists[g * N_NODES + p] = i;
    }
}

// ---------------------------------------------------------------- masked softmax attention + PV, one block per node i
// writes bf16 (feeds the second MFMA GEMM)
__global__ __launch_bounds__(256) void attn_kernel(
    const float* __restrict__ Wh, const float* __restrict__ s1, const float* __restrict__ s2,
    const int* __restrict__ h_id, const int* __restrict__ cnt, const int* __restrict__ lists,
    __hip_bfloat16* __restrict__ out)
{
    const int i = blockIdx.x;
    const int t = threadIdx.x;
    const int lane = t & 63, wv = t >> 6;

    __shared__ float s1i[8];
    __shared__ float m_sh[8];
    __shared__ float S_sh[8];
    __shared__ float wred[4][8];
    __shared__ float wbuf[256][8];
    __shared__ int jbuf[256];

    const int g = h_id[i];
    const int ng = cnt[g];
    const int* gl = lists + g * N_NODES;

    if (t < 8) s1i[t] = s1[i * 8 + t];
    __syncthreads();

    // ---- phase 1: per-head max over group
    float lv[8];
#pragma unroll
    for (int h = 0; h < 8; h++) lv[h] = -1e30f;
    for (int idx = t; idx < ng; idx += 256) {
        int j = gl[idx];
        float sq = s1i[j >> 8];
#pragma unroll
        for (int h = 0; h < 8; h++) {
            float x = sq + s2[j * 8 + h];
            float ev = (x >= 0.f ? x : ALPHA * x) * SCALE;
            lv[h] = fmaxf(lv[h], ev);
        }
    }
#pragma unroll
    for (int h = 0; h < 8; h++) {
        for (int o = 32; o > 0; o >>= 1) lv[h] = fmaxf(lv[h], __shfl_xor(lv[h], o));
    }
    if (lane == 0) {
#pragma unroll
        for (int h = 0; h < 8; h++) wred[wv][h] = lv[h];
    }
    __syncthreads();
    if (t < 8) m_sh[t] = fmaxf(fmaxf(wred[0][t], wred[1][t]), fmaxf(wred[2][t], wred[3][t]));
    __syncthreads();

    // ---- phase 2: per-head sum of exp
#pragma unroll
    for (int h = 0; h < 8; h++) lv[h] = 0.f;
    for (int idx = t; idx < ng; idx += 256) {
        int j = gl[idx];
        float sq = s1i[j >> 8];
#pragma unroll
        for (int h = 0; h < 8; h++) {
            float x = sq + s2[j * 8 + h];
            float ev = (x >= 0.f ? x : ALPHA * x) * SCALE;
            lv[h] += __expf(ev - m_sh[h]);
        }
    }
#pragma unroll
    for (int h = 0; h < 8; h++) {
        for (int o = 32; o > 0; o >>= 1) lv[h] += __shfl_xor(lv[h], o);
    }
    if (lane == 0) {
#pragma unroll
        for (int h = 0; h < 8; h++) wred[wv][h] = lv[h];
    }
    __syncthreads();
    if (t < 8) S_sh[t] = 1.f / (wred[0][t] + wred[1][t] + wred[2][t] + wred[3][t]);
    __syncthreads();

    // ---- phase 3: out[i, :] = sum_j w[j,h] * Wh[j, :]
    const int c0 = t, c1 = t + 256, c2 = t + 512;
    const int h0 = c0 / DH, h1 = c1 / DH, h2 = c2 / DH;
    float acc0 = 0.f, acc1 = 0.f, acc2 = 0.f;
    for (int base = 0; base < ng; base += 256) {
        const int cn = min(256, ng - base);
        __syncthreads();
        if (t < cn) {
            int j = gl[base + t];
            jbuf[t] = j;
            float sq = s1i[j >> 8];
#pragma unroll
            for (int h = 0; h < 8; h++) {
                float x = sq + s2[j * 8 + h];
                float ev = (x >= 0.f ? x : ALPHA * x) * SCALE;
                wbuf[t][h] = __expf(ev - m_sh[h]) * S_sh[h];
            }
        }
        __syncthreads();
        for (int c = 0; c < cn; c++) {
            const float* wr = Wh + (size_t)jbuf[c] * EMB;
            acc0 += wbuf[c][h0] * wr[c0];
            acc1 += wbuf[c][h1] * wr[c1];
            acc2 += wbuf[c][h2] * wr[c2];
        }
    }
    out[(size_t)i * EMB + c0] = __float2bfloat16(acc0);
    out[(size_t)i * EMB + c1] = __float2bfloat16(acc1);
    out[(size_t)i * EMB + c2] = __float2bfloat16(acc2);
}

// ---------------------------------------------------------------- launch
extern "C" void kernel_launch(void* const* d_in, const int* in_sizes, int n_in,
                              void* d_out, int out_size, void* d_ws, size_t ws_size,
                              hipStream_t stream)
{
    const float* eh     = (const float*)d_in[0];
    const float* er     = (const float*)d_in[1];
    const float* et     = (const float*)d_in[2];
    const int*   h_id   = (const int*)d_in[3];
    const float* W_w    = (const float*)d_in[4];
    const float* a      = (const float*)d_in[5];
    const float* proj_w = (const float*)d_in[6];
    const float* proj_b = (const float*)d_in[7];
    const float* skip_w = (const float*)d_in[8];
    const float* skip_b = (const float*)d_in[9];
    float* out = (float*)d_out;   // reference output dtype is f32

    char* ws = (char*)d_ws;
    // layout (bytes):
    //   e bf16        @ 0          3,145,728
    //   Wh f32        @ 3,145,728  6,291,456
    //   attn bf16     @ 9,437,184  3,145,728
    //   W_w bf16      @ 12,582,912 1,179,648
    //   proj_w bf16   @ 13,762,560 1,179,648
    //   skip_w bf16   @ 14,942,208 1,179,648
    //   s1 f32        @ 16,121,856 65,536
    //   s2 f32        @ 16,187,392 65,536
    //   cnt           @ 16,252,928 128
    //   lists         @ 16,253,056 262,144
    __hip_bfloat16* e_ws   = (__hip_bfloat16*)(ws);
    float*          Wh_ws  = (float*)(ws + 3145728);
    __hip_bfloat16* at_ws  = (__hip_bfloat16*)(ws + 9437184);
    __hip_bfloat16* Wb_ws  = (__hip_bfloat16*)(ws + 12582912);
    __hip_bfloat16* Pb_ws  = (__hip_bfloat16*)(ws + 13762560);
    __hip_bfloat16* Sb_ws  = (__hip_bfloat16*)(ws + 14942208);
    float*          s1_ws  = (float*)(ws + 16121856);
    float*          s2_ws  = (float*)(ws + 16187392);
    int*            cnt_ws = (int*)(ws + 16252928);
    int*            lst_ws = (int*)(ws + 16253056);

    concat_cast_kernel<<<1536, 256, 0, stream>>>(eh, er, et, e_ws, cnt_ws);
    cast_w_kernel<<<1728, 256, 0, stream>>>(W_w, proj_w, skip_w, Wb_ws, Pb_ws, Sb_ws);

    // Wh = e @ W_w^T  (f32 output)
    gemm_nt_kernel<<<dim3(12, 32), 256, 0, stream>>>(
        e_ws, Wb_ws, EMB, nullptr, nullptr, 0, nullptr, nullptr, Wh_ws, EMB);

    s12_kernel<<<64, 256, 0, stream>>>(Wh_ws, a, s1_ws, s2_ws);
    group_kernel<<<8, 256, 0, stream>>>(h_id, cnt_ws, lst_ws);

    attn_kernel<<<N_NODES, 256, 0, stream>>>(Wh_ws, s1_ws, s2_ws, h_id, cnt_ws, lst_ws, at_ws);

    // out = attn @ proj_w^T + e @ skip_w^T + (proj_b + skip_b)  (f32 output)
    gemm_nt_kernel<<<dim3(12, 32), 256, 0, stream>>>(
        at_ws, Pb_ws, EMB, e_ws, Sb_ws, EMB, proj_b, skip_b, out, EMB);
}

// Round 5
// 143.396 us; speedup vs baseline: 1.3032x; 1.3032x over previous
//
#include <hip/hip_runtime.h>
#include <hip/hip_bf16.h>

#define N_NODES 2048
#define EMB 768
#define NH 8
#define DH 96
#define ALPHA 0.2f
#define SCALE 0.10206207261596575f  // 96^-0.5

typedef __bf16 bf16x8 __attribute__((ext_vector_type(8)));
typedef float f32x4 __attribute__((ext_vector_type(4)));
typedef __attribute__((address_space(3))) unsigned int lds_u32;
typedef __attribute__((address_space(1))) const unsigned int glb_u32;

union pack4 { ushort4 u; __hip_bfloat16 h[4]; };

// ---------------------------------------------------------------- prep: concat-cast e + cast 3 weights + zero cnt
__global__ __launch_bounds__(256) void prep_kernel(
    const float* __restrict__ eh, const float* __restrict__ er, const float* __restrict__ et,
    const float* __restrict__ W0, const float* __restrict__ W1, const float* __restrict__ W2,
    __hip_bfloat16* __restrict__ e, __hip_bfloat16* __restrict__ o0,
    __hip_bfloat16* __restrict__ o1, __hip_bfloat16* __restrict__ o2, int* __restrict__ cnt)
{
    const int b = blockIdx.x;
    const int gtid = b * 256 + threadIdx.x;
    if (gtid < 32) cnt[gtid] = 0;
    const float* src;
    __hip_bfloat16* dst;
    if (b < 1536) {                       // e = concat(eh,er,et), 2048*768 elems
        int idx = gtid * 4;
        int i = idx / EMB, c = idx % EMB;
        if (c < 256)      src = eh + i * 256 + c;
        else if (c < 512) src = er + i * 256 + (c - 256);
        else              src = et + i * 256 + (c - 512);
        dst = e + (size_t)i * EMB + c;
    } else {                              // three 768x768 weights
        const int WSZ = EMB * EMB;
        int idx = (gtid - 1536 * 256) * 4;
        if (idx < WSZ)          { src = W0 + idx;           dst = o0 + idx; }
        else if (idx < 2 * WSZ) { src = W1 + idx - WSZ;     dst = o1 + idx - WSZ; }
        else                    { src = W2 + idx - 2 * WSZ; dst = o2 + idx - 2 * WSZ; }
    }
    float4 v = *reinterpret_cast<const float4*>(src);
    pack4 p;
    p.h[0] = __float2bfloat16(v.x);
    p.h[1] = __float2bfloat16(v.y);
    p.h[2] = __float2bfloat16(v.z);
    p.h[3] = __float2bfloat16(v.w);
    *reinterpret_cast<ushort4*>(dst) = p.u;
}

// ---------------------------------------------------------------- async-staged MFMA GEMM
// C = A1@B1^T [+ A2@B2^T] [+ bias1+bias2], all mats row-major ld=EMB, M=2048, N=EMB.
// 64x64 tile/block, 4 waves (2x2), BK=64, LDS double-buffer via global_load_lds(16B).
// LDS layout: 16B chunk (row,cb) stored at chunk index row*8 + (cb ^ (row&7)) -> conflict-free
// ds_read_b128 fragments AND row-contiguous staging sources.
__device__ __forceinline__ void stage_tile(
    const __hip_bfloat16* __restrict__ src, int row0, int k0,
    __hip_bfloat16* lds, int wave, int lane)
{
#pragma unroll
    for (int r = 0; r < 2; r++) {
        const int L = wave * 128 + r * 64 + lane;   // chunk index in tile
        const int row = L >> 3;
        const int cb = (L & 7) ^ (row & 7);         // un-swizzle -> source col-block
        const __hip_bfloat16* g = src + (size_t)(row0 + row) * EMB + k0 + cb * 8;
        __builtin_amdgcn_global_load_lds(
            (glb_u32*)g, (lds_u32*)(lds + (size_t)(wave * 128 + r * 64) * 8), 16, 0, 0);
    }
}

__global__ __launch_bounds__(256) void gemm_nt_kernel(
    const __hip_bfloat16* __restrict__ A1, const __hip_bfloat16* __restrict__ B1, int ns1,
    const __hip_bfloat16* __restrict__ A2, const __hip_bfloat16* __restrict__ B2, int ns2,
    const float* __restrict__ bias1, const float* __restrict__ bias2,
    float* __restrict__ Cf)
{
    __shared__ __attribute__((aligned(16))) __hip_bfloat16 sm[2][2][4096]; // [buf][A/B][64x64]

    const int t = threadIdx.x;
    const int lane = t & 63, wave = t >> 6;
    const int wm = wave >> 1, wn = wave & 1;
    const int bm = blockIdx.y * 64, bn = blockIdx.x * 64;
    const int l15 = lane & 15, quad = lane >> 4;
    const int NS = ns1 + ns2;

    f32x4 acc00 = {0.f,0.f,0.f,0.f}, acc01 = {0.f,0.f,0.f,0.f};
    f32x4 acc10 = {0.f,0.f,0.f,0.f}, acc11 = {0.f,0.f,0.f,0.f};

    // prologue: stage 0
    stage_tile(A1, bm, 0, &sm[0][0][0], wave, lane);
    stage_tile(B1, bn, 0, &sm[0][1][0], wave, lane);

    const int rA = wm * 32 + l15;   // A rows (a0: rA, a1: rA+16; same &7)
    const int rB = wn * 32 + l15;
    const int xa = rA & 7, xb = rB & 7;

    for (int s = 0; s < NS; s++) {
        __syncthreads();                       // drains vmcnt (stage s ready) + barrier
        if (s + 1 < NS) {                      // prefetch stage s+1 while computing s
            const int sn = s + 1;
            const __hip_bfloat16* As = (sn < ns1) ? A1 : A2;
            const __hip_bfloat16* Bs = (sn < ns1) ? B1 : B2;
            const int k0 = ((sn < ns1) ? sn : sn - ns1) * 64;
            stage_tile(As, bm, k0, &sm[sn & 1][0][0], wave, lane);
            stage_tile(Bs, bn, k0, &sm[sn & 1][1][0], wave, lane);
        }
        const __hip_bfloat16* At = &sm[s & 1][0][0];
        const __hip_bfloat16* Bt = &sm[s & 1][1][0];
#pragma unroll
        for (int ks = 0; ks < 2; ks++) {
            const int cq = ks * 4 + quad;
            bf16x8 a0 = *(const bf16x8*)(At + ((size_t)rA        * 8 + (cq ^ xa)) * 8);
            bf16x8 a1 = *(const bf16x8*)(At + ((size_t)(rA + 16) * 8 + (cq ^ xa)) * 8);
            bf16x8 b0 = *(const bf16x8*)(Bt + ((size_t)rB        * 8 + (cq ^ xb)) * 8);
            bf16x8 b1 = *(const bf16x8*)(Bt + ((size_t)(rB + 16) * 8 + (cq ^ xb)) * 8);
            acc00 = __builtin_amdgcn_mfma_f32_16x16x32_bf16(a0, b0, acc00, 0, 0, 0);
            acc01 = __builtin_amdgcn_mfma_f32_16x16x32_bf16(a0, b1, acc01, 0, 0, 0);
            acc10 = __builtin_amdgcn_mfma_f32_16x16x32_bf16(a1, b0, acc10, 0, 0, 0);
            acc11 = __builtin_amdgcn_mfma_f32_16x16x32_bf16(a1, b1, acc11, 0, 0, 0);
        }
    }

    const int col0 = bn + wn * 32 + l15;
    const int col1 = col0 + 16;
    float bv0 = 0.f, bv1 = 0.f;
    if (bias1 != nullptr) {
        bv0 = bias1[col0] + bias2[col0];
        bv1 = bias1[col1] + bias2[col1];
    }
    const int r0 = bm + wm * 32 + quad * 4;
#pragma unroll
    for (int r = 0; r < 4; r++) {
        const int row0 = r0 + r, row1 = r0 + 16 + r;
        Cf[(size_t)row0 * EMB + col0] = acc00[r] + bv0;
        Cf[(size_t)row0 * EMB + col1] = acc01[r] + bv1;
        Cf[(size_t)row1 * EMB + col0] = acc10[r] + bv0;
        Cf[(size_t)row1 * EMB + col1] = acc11[r] + bv1;
    }
}

// ---------------------------------------------------------------- s1/s2 + group lists (fused)
__global__ __launch_bounds__(256) void s12g_kernel(
    const float* __restrict__ Wh, const float* __restrict__ a,
    float* __restrict__ s1, float* __restrict__ s2,
    const int* __restrict__ h_id, int* __restrict__ cnt, int* __restrict__ lists)
{
    int gid = blockIdx.x * 256 + threadIdx.x;  // [0, N*NH)
    if (gid < N_NODES) {
        int g = h_id[gid];
        int p = atomicAdd(&cnt[g], 1);
        lists[g * N_NODES + p] = gid;
    }
    int i = gid >> 3, h = gid & 7;
    const float* wr = Wh + (size_t)i * EMB + h * DH;
    float acc1 = 0.f, acc2 = 0.f;
    for (int d = 0; d < DH; d++) {
        float w = wr[d];
        acc1 += w * a[d];
        acc2 += w * a[DH + d];
    }
    s1[gid] = acc1;
    s2[gid] = acc2;
}

// ---------------------------------------------------------------- masked softmax attention + PV, one block per node i
__global__ __launch_bounds__(256) void attn_kernel(
    const float* __restrict__ Wh, const float* __restrict__ s1, const float* __restrict__ s2,
    const int* __restrict__ h_id, const int* __restrict__ cnt, const int* __restrict__ lists,
    __hip_bfloat16* __restrict__ out)
{
    const int i = blockIdx.x;
    const int t = threadIdx.x;
    const int lane = t & 63, wv = t >> 6;

    __shared__ float s1i[8];
    __shared__ float m_sh[8];
    __shared__ float S_sh[8];
    __shared__ float wred[4][8];
    __shared__ float wbuf[256][8];
    __shared__ int jbuf[256];

    const int g = h_id[i];
    const int ng = cnt[g];
    const int* gl = lists + g * N_NODES;

    if (t < 8) s1i[t] = s1[i * 8 + t];
    __syncthreads();

    float lv[8];
#pragma unroll
    for (int h = 0; h < 8; h++) lv[h] = -1e30f;
    for (int idx = t; idx < ng; idx += 256) {
        int j = gl[idx];
        float sq = s1i[j >> 8];
#pragma unroll
        for (int h = 0; h < 8; h++) {
            float x = sq + s2[j * 8 + h];
            float ev = (x >= 0.f ? x : ALPHA * x) * SCALE;
            lv[h] = fmaxf(lv[h], ev);
        }
    }
#pragma unroll
    for (int h = 0; h < 8; h++) {
        for (int o = 32; o > 0; o >>= 1) lv[h] = fmaxf(lv[h], __shfl_xor(lv[h], o));
    }
    if (lane == 0) {
#pragma unroll
        for (int h = 0; h < 8; h++) wred[wv][h] = lv[h];
    }
    __syncthreads();
    if (t < 8) m_sh[t] = fmaxf(fmaxf(wred[0][t], wred[1][t]), fmaxf(wred[2][t], wred[3][t]));
    __syncthreads();

#pragma unroll
    for (int h = 0; h < 8; h++) lv[h] = 0.f;
    for (int idx = t; idx < ng; idx += 256) {
        int j = gl[idx];
        float sq = s1i[j >> 8];
#pragma unroll
        for (int h = 0; h < 8; h++) {
            float x = sq + s2[j * 8 + h];
            float ev = (x >= 0.f ? x : ALPHA * x) * SCALE;
            lv[h] += __expf(ev - m_sh[h]);
        }
    }
#pragma unroll
    for (int h = 0; h < 8; h++) {
        for (int o = 32; o > 0; o >>= 1) lv[h] += __shfl_xor(lv[h], o);
    }
    if (lane == 0) {
#pragma unroll
        for (int h = 0; h < 8; h++) wred[wv][h] = lv[h];
    }
    __syncthreads();
    if (t < 8) S_sh[t] = 1.f / (wred[0][t] + wred[1][t] + wred[2][t] + wred[3][t]);
    __syncthreads();

    const int c0 = t, c1 = t + 256, c2 = t + 512;
    const int h0 = c0 / DH, h1 = c1 / DH, h2 = c2 / DH;
    float acc0 = 0.f, acc1 = 0.f, acc2 = 0.f;
    for (int base = 0; base < ng; base += 256) {
        const int cn = min(256, ng - base);
        __syncthreads();
        if (t < cn) {
            int j = gl[base + t];
            jbuf[t] = j;
            float sq = s1i[j >> 8];
#pragma unroll
            for (int h = 0; h < 8; h++) {
                float x = sq + s2[j * 8 + h];
                float ev = (x >= 0.f ? x : ALPHA * x) * SCALE;
                wbuf[t][h] = __expf(ev - m_sh[h]) * S_sh[h];
            }
        }
        __syncthreads();
        for (int c = 0; c < cn; c++) {
            const float* wr = Wh + (size_t)jbuf[c] * EMB;
            acc0 += wbuf[c][h0] * wr[c0];
            acc1 += wbuf[c][h1] * wr[c1];
            acc2 += wbuf[c][h2] * wr[c2];
        }
    }
    out[(size_t)i * EMB + c0] = __float2bfloat16(acc0);
    out[(size_t)i * EMB + c1] = __float2bfloat16(acc1);
    out[(size_t)i * EMB + c2] = __float2bfloat16(acc2);
}

// ---------------------------------------------------------------- launch
extern "C" void kernel_launch(void* const* d_in, const int* in_sizes, int n_in,
                              void* d_out, int out_size, void* d_ws, size_t ws_size,
                              hipStream_t stream)
{
    const float* eh     = (const float*)d_in[0];
    const float* er     = (const float*)d_in[1];
    const float* et     = (const float*)d_in[2];
    const int*   h_id   = (const int*)d_in[3];
    const float* W_w    = (const float*)d_in[4];
    const float* a      = (const float*)d_in[5];
    const float* proj_w = (const float*)d_in[6];
    const float* proj_b = (const float*)d_in[7];
    const float* skip_w = (const float*)d_in[8];
    const float* skip_b = (const float*)d_in[9];
    float* out = (float*)d_out;   // reference output dtype is f32

    char* ws = (char*)d_ws;
    __hip_bfloat16* e_ws   = (__hip_bfloat16*)(ws);
    float*          Wh_ws  = (float*)(ws + 3145728);
    __hip_bfloat16* at_ws  = (__hip_bfloat16*)(ws + 9437184);
    __hip_bfloat16* Wb_ws  = (__hip_bfloat16*)(ws + 12582912);
    __hip_bfloat16* Pb_ws  = (__hip_bfloat16*)(ws + 13762560);
    __hip_bfloat16* Sb_ws  = (__hip_bfloat16*)(ws + 14942208);
    float*          s1_ws  = (float*)(ws + 16121856);
    float*          s2_ws  = (float*)(ws + 16187392);
    int*            cnt_ws = (int*)(ws + 16252928);
    int*            lst_ws = (int*)(ws + 16253056);

    prep_kernel<<<3264, 256, 0, stream>>>(eh, er, et, W_w, proj_w, skip_w,
                                          e_ws, Wb_ws, Pb_ws, Sb_ws, cnt_ws);

    // Wh = e @ W_w^T  (f32 output)
    gemm_nt_kernel<<<dim3(12, 32), 256, 0, stream>>>(
        e_ws, Wb_ws, 12, nullptr, nullptr, 0, nullptr, nullptr, Wh_ws);

    s12g_kernel<<<64, 256, 0, stream>>>(Wh_ws, a, s1_ws, s2_ws, h_id, cnt_ws, lst_ws);

    attn_kernel<<<N_NODES, 256, 0, stream>>>(Wh_ws, s1_ws, s2_ws, h_id, cnt_ws, lst_ws, at_ws);

    // out = attn @ proj_w^T + e @ skip_w^T + (proj_b + skip_b)  (f32 output)
    gemm_nt_kernel<<<dim3(12, 32), 256, 0, stream>>>(
        at_ws, Pb_ws, 12, e_ws, Sb_ws, 12, proj_b, skip_b, out);
}

// Round 6
// 142.325 us; speedup vs baseline: 1.3130x; 1.0075x over previous
//
#include <hip/hip_runtime.h>
#include <hip/hip_bf16.h>

#define N_NODES 2048
#define EMB 768
#define NH 8
#define DH 96
#define ALPHA 0.2f
#define SCALE 0.10206207261596575f  // 96^-0.5
#define NGMAX 192                   // max group size supported (binomial(2048,1/32): mean 64, sigma 7.9 -> 192 is >16 sigma)

typedef __bf16 bf16x8 __attribute__((ext_vector_type(8)));
typedef float f32x4 __attribute__((ext_vector_type(4)));
typedef __attribute__((address_space(3))) unsigned int lds_u32;
typedef __attribute__((address_space(1))) const unsigned int glb_u32;

union pack4 { ushort4 u; __hip_bfloat16 h[4]; };

// ---------------------------------------------------------------- prep: concat-cast e + cast 3 weights + zero cnt
__global__ __launch_bounds__(256) void prep_kernel(
    const float* __restrict__ eh, const float* __restrict__ er, const float* __restrict__ et,
    const float* __restrict__ W0, const float* __restrict__ W1, const float* __restrict__ W2,
    __hip_bfloat16* __restrict__ e, __hip_bfloat16* __restrict__ o0,
    __hip_bfloat16* __restrict__ o1, __hip_bfloat16* __restrict__ o2, int* __restrict__ cnt)
{
    const int b = blockIdx.x;
    const int gtid = b * 256 + threadIdx.x;
    if (gtid < 32) cnt[gtid] = 0;
    const float* src;
    __hip_bfloat16* dst;
    if (b < 1536) {                       // e = concat(eh,er,et), 2048*768 elems
        int idx = gtid * 4;
        int i = idx / EMB, c = idx % EMB;
        if (c < 256)      src = eh + i * 256 + c;
        else if (c < 512) src = er + i * 256 + (c - 256);
        else              src = et + i * 256 + (c - 512);
        dst = e + (size_t)i * EMB + c;
    } else {                              // three 768x768 weights
        const int WSZ = EMB * EMB;
        int idx = (gtid - 1536 * 256) * 4;
        if (idx < WSZ)          { src = W0 + idx;           dst = o0 + idx; }
        else if (idx < 2 * WSZ) { src = W1 + idx - WSZ;     dst = o1 + idx - WSZ; }
        else                    { src = W2 + idx - 2 * WSZ; dst = o2 + idx - 2 * WSZ; }
    }
    float4 v = *reinterpret_cast<const float4*>(src);
    pack4 p;
    p.h[0] = __float2bfloat16(v.x);
    p.h[1] = __float2bfloat16(v.y);
    p.h[2] = __float2bfloat16(v.z);
    p.h[3] = __float2bfloat16(v.w);
    *reinterpret_cast<ushort4*>(dst) = p.u;
}

// ---------------------------------------------------------------- async-staged MFMA GEMM (unchanged from R5)
__device__ __forceinline__ void stage_tile(
    const __hip_bfloat16* __restrict__ src, int row0, int k0,
    __hip_bfloat16* lds, int wave, int lane)
{
#pragma unroll
    for (int r = 0; r < 2; r++) {
        const int L = wave * 128 + r * 64 + lane;   // chunk index in tile
        const int row = L >> 3;
        const int cb = (L & 7) ^ (row & 7);         // un-swizzle -> source col-block
        const __hip_bfloat16* g = src + (size_t)(row0 + row) * EMB + k0 + cb * 8;
        __builtin_amdgcn_global_load_lds(
            (glb_u32*)g, (lds_u32*)(lds + (size_t)(wave * 128 + r * 64) * 8), 16, 0, 0);
    }
}

__global__ __launch_bounds__(256) void gemm_nt_kernel(
    const __hip_bfloat16* __restrict__ A1, const __hip_bfloat16* __restrict__ B1, int ns1,
    const __hip_bfloat16* __restrict__ A2, const __hip_bfloat16* __restrict__ B2, int ns2,
    const float* __restrict__ bias1, const float* __restrict__ bias2,
    float* __restrict__ Cf)
{
    __shared__ __attribute__((aligned(16))) __hip_bfloat16 sm[2][2][4096]; // [buf][A/B][64x64]

    const int t = threadIdx.x;
    const int lane = t & 63, wave = t >> 6;
    const int wm = wave >> 1, wn = wave & 1;
    const int bm = blockIdx.y * 64, bn = blockIdx.x * 64;
    const int l15 = lane & 15, quad = lane >> 4;
    const int NS = ns1 + ns2;

    f32x4 acc00 = {0.f,0.f,0.f,0.f}, acc01 = {0.f,0.f,0.f,0.f};
    f32x4 acc10 = {0.f,0.f,0.f,0.f}, acc11 = {0.f,0.f,0.f,0.f};

    stage_tile(A1, bm, 0, &sm[0][0][0], wave, lane);
    stage_tile(B1, bn, 0, &sm[0][1][0], wave, lane);

    const int rA = wm * 32 + l15;
    const int rB = wn * 32 + l15;
    const int xa = rA & 7, xb = rB & 7;

    for (int s = 0; s < NS; s++) {
        __syncthreads();
        if (s + 1 < NS) {
            const int sn = s + 1;
            const __hip_bfloat16* As = (sn < ns1) ? A1 : A2;
            const __hip_bfloat16* Bs = (sn < ns1) ? B1 : B2;
            const int k0 = ((sn < ns1) ? sn : sn - ns1) * 64;
            stage_tile(As, bm, k0, &sm[sn & 1][0][0], wave, lane);
            stage_tile(Bs, bn, k0, &sm[sn & 1][1][0], wave, lane);
        }
        const __hip_bfloat16* At = &sm[s & 1][0][0];
        const __hip_bfloat16* Bt = &sm[s & 1][1][0];
#pragma unroll
        for (int ks = 0; ks < 2; ks++) {
            const int cq = ks * 4 + quad;
            bf16x8 a0 = *(const bf16x8*)(At + ((size_t)rA        * 8 + (cq ^ xa)) * 8);
            bf16x8 a1 = *(const bf16x8*)(At + ((size_t)(rA + 16) * 8 + (cq ^ xa)) * 8);
            bf16x8 b0 = *(const bf16x8*)(Bt + ((size_t)rB        * 8 + (cq ^ xb)) * 8);
            bf16x8 b1 = *(const bf16x8*)(Bt + ((size_t)(rB + 16) * 8 + (cq ^ xb)) * 8);
            acc00 = __builtin_amdgcn_mfma_f32_16x16x32_bf16(a0, b0, acc00, 0, 0, 0);
            acc01 = __builtin_amdgcn_mfma_f32_16x16x32_bf16(a0, b1, acc01, 0, 0, 0);
            acc10 = __builtin_amdgcn_mfma_f32_16x16x32_bf16(a1, b0, acc10, 0, 0, 0);
            acc11 = __builtin_amdgcn_mfma_f32_16x16x32_bf16(a1, b1, acc11, 0, 0, 0);
        }
    }

    const int col0 = bn + wn * 32 + l15;
    const int col1 = col0 + 16;
    float bv0 = 0.f, bv1 = 0.f;
    if (bias1 != nullptr) {
        bv0 = bias1[col0] + bias2[col0];
        bv1 = bias1[col1] + bias2[col1];
    }
    const int r0 = bm + wm * 32 + quad * 4;
#pragma unroll
    for (int r = 0; r < 4; r++) {
        const int row0 = r0 + r, row1 = r0 + 16 + r;
        Cf[(size_t)row0 * EMB + col0] = acc00[r] + bv0;
        Cf[(size_t)row0 * EMB + col1] = acc01[r] + bv1;
        Cf[(size_t)row1 * EMB + col0] = acc10[r] + bv0;
        Cf[(size_t)row1 * EMB + col1] = acc11[r] + bv1;
    }
}

// ---------------------------------------------------------------- s1/s2 + group lists (fused)
__global__ __launch_bounds__(256) void s12g_kernel(
    const float* __restrict__ Wh, const float* __restrict__ a,
    float* __restrict__ s1, float* __restrict__ s2,
    const int* __restrict__ h_id, int* __restrict__ cnt, int* __restrict__ lists)
{
    int gid = blockIdx.x * 256 + threadIdx.x;  // [0, N*NH)
    if (gid < N_NODES) {
        int g = h_id[gid];
        int p = atomicAdd(&cnt[g], 1);
        lists[g * N_NODES + p] = gid;
    }
    int i = gid >> 3, h = gid & 7;
    const float* wr = Wh + (size_t)i * EMB + h * DH;
    float acc1 = 0.f, acc2 = 0.f;
    for (int d = 0; d < DH; d++) {
        float w = wr[d];
        acc1 += w * a[d];
        acc2 += w * a[DH + d];
    }
    s1[gid] = acc1;
    s2[gid] = acc2;
}

// ---------------------------------------------------------------- attention: block per (group, head, col-half)
// Each block stages its group's Wh column slice in LDS ONCE (kills the 64x
// re-read of the old block-per-node version), computes softmax stats from the
// rank-1 score structure x = s1[i, q(j)] + s2[j,h], then thread t computes
// output row jb[t] over 48 cols with Whg broadcast reads (conflict-free).
__global__ __launch_bounds__(256) void attn_kernel(
    const float* __restrict__ Wh, const float* __restrict__ s1, const float* __restrict__ s2,
    const int* __restrict__ cnt, const int* __restrict__ lists,
    __hip_bfloat16* __restrict__ out)
{
    const int g  = blockIdx.x & 31;
    const int h  = (blockIdx.x >> 5) & 7;
    const int dh = blockIdx.x >> 8;          // 0/1 -> cols [dh*48, dh*48+48)
    const int t  = threadIdx.x;

    __shared__ int   jb[NGMAX];
    __shared__ int   qg[NGMAX];
    __shared__ float s2g[NGMAX];
    __shared__ float s1g[NGMAX][9];          // pad 9: stride-8 would 16-way conflict
    __shared__ float Whg[NGMAX][48];         // 16B-aligned rows -> ds_read_b128

    const int ng = min(cnt[g], NGMAX);
    const int* gl = lists + g * N_NODES;

    for (int j = t; j < ng; j += 256) {
        int node = gl[j];
        jb[j]  = node;
        qg[j]  = node >> 8;
        s2g[j] = s2[node * 8 + h];
        float4 v0 = *reinterpret_cast<const float4*>(s1 + node * 8);
        float4 v1 = *reinterpret_cast<const float4*>(s1 + node * 8 + 4);
        s1g[j][0] = v0.x; s1g[j][1] = v0.y; s1g[j][2] = v0.z; s1g[j][3] = v0.w;
        s1g[j][4] = v1.x; s1g[j][5] = v1.y; s1g[j][6] = v1.z; s1g[j][7] = v1.w;
    }
    __syncthreads();
    for (int idx = t; idx < ng * 12; idx += 256) {
        int jc = idx / 12, dq = idx % 12;
        float4 v = *reinterpret_cast<const float4*>(
            Wh + (size_t)jb[jc] * EMB + h * DH + dh * 48 + dq * 4);
        *reinterpret_cast<float4*>(&Whg[jc][dq * 4]) = v;
    }
    __syncthreads();

    if (t < ng) {
        // softmax stats for node i = t
        float m = -1e30f;
        for (int j = 0; j < ng; j++) {
            float x = s1g[t][qg[j]] + s2g[j];
            float ev = (x >= 0.f ? x : ALPHA * x) * SCALE;
            m = fmaxf(m, ev);
        }
        float S = 0.f;
        for (int j = 0; j < ng; j++) {
            float x = s1g[t][qg[j]] + s2g[j];
            float ev = (x >= 0.f ? x : ALPHA * x) * SCALE;
            S += __expf(ev - m);
        }
        const float ri = 1.f / S;

        float acc[48];
#pragma unroll
        for (int d = 0; d < 48; d++) acc[d] = 0.f;
        for (int j = 0; j < ng; j++) {
            float x = s1g[t][qg[j]] + s2g[j];
            float ev = (x >= 0.f ? x : ALPHA * x) * SCALE;
            float p = __expf(ev - m) * ri;
#pragma unroll
            for (int d = 0; d < 48; d++) acc[d] += p * Whg[j][d];
        }
        __hip_bfloat16* po = out + (size_t)jb[t] * EMB + h * DH + dh * 48;
#pragma unroll
        for (int d = 0; d < 48; d += 4) {
            pack4 pk;
            pk.h[0] = __float2bfloat16(acc[d]);
            pk.h[1] = __float2bfloat16(acc[d + 1]);
            pk.h[2] = __float2bfloat16(acc[d + 2]);
            pk.h[3] = __float2bfloat16(acc[d + 3]);
            *reinterpret_cast<ushort4*>(po + d) = pk.u;
        }
    }
}

// ---------------------------------------------------------------- launch
extern "C" void kernel_launch(void* const* d_in, const int* in_sizes, int n_in,
                              void* d_out, int out_size, void* d_ws, size_t ws_size,
                              hipStream_t stream)
{
    const float* eh     = (const float*)d_in[0];
    const float* er     = (const float*)d_in[1];
    const float* et     = (const float*)d_in[2];
    const int*   h_id   = (const int*)d_in[3];
    const float* W_w    = (const float*)d_in[4];
    const float* a      = (const float*)d_in[5];
    const float* proj_w = (const float*)d_in[6];
    const float* proj_b = (const float*)d_in[7];
    const float* skip_w = (const float*)d_in[8];
    const float* skip_b = (const float*)d_in[9];
    float* out = (float*)d_out;   // reference output dtype is f32

    char* ws = (char*)d_ws;
    __hip_bfloat16* e_ws   = (__hip_bfloat16*)(ws);
    float*          Wh_ws  = (float*)(ws + 3145728);
    __hip_bfloat16* at_ws  = (__hip_bfloat16*)(ws + 9437184);
    __hip_bfloat16* Wb_ws  = (__hip_bfloat16*)(ws + 12582912);
    __hip_bfloat16* Pb_ws  = (__hip_bfloat16*)(ws + 13762560);
    __hip_bfloat16* Sb_ws  = (__hip_bfloat16*)(ws + 14942208);
    float*          s1_ws  = (float*)(ws + 16121856);
    float*          s2_ws  = (float*)(ws + 16187392);
    int*            cnt_ws = (int*)(ws + 16252928);
    int*            lst_ws = (int*)(ws + 16253056);

    prep_kernel<<<3264, 256, 0, stream>>>(eh, er, et, W_w, proj_w, skip_w,
                                          e_ws, Wb_ws, Pb_ws, Sb_ws, cnt_ws);

    // Wh = e @ W_w^T  (f32 output)
    gemm_nt_kernel<<<dim3(12, 32), 256, 0, stream>>>(
        e_ws, Wb_ws, 12, nullptr, nullptr, 0, nullptr, nullptr, Wh_ws);

    s12g_kernel<<<64, 256, 0, stream>>>(Wh_ws, a, s1_ws, s2_ws, h_id, cnt_ws, lst_ws);

    attn_kernel<<<512, 256, 0, stream>>>(Wh_ws, s1_ws, s2_ws, cnt_ws, lst_ws, at_ws);

    // out = attn @ proj_w^T + e @ skip_w^T + (proj_b + skip_b)  (f32 output)
    gemm_nt_kernel<<<dim3(12, 32), 256, 0, stream>>>(
        at_ws, Pb_ws, 12, e_ws, Sb_ws, 12, proj_b, skip_b, out);
}